// Round 5
// baseline (315.765 us; speedup 1.0000x reference)
//
#include <hip/hip_runtime.h>
#include <hip/hip_bf16.h>
#include <cstdint>
#include <cstddef>

typedef __hip_bfloat16 bf16;
typedef __attribute__((ext_vector_type(8))) short short8;   // 8 bf16 = 4 VGPRs
typedef __attribute__((ext_vector_type(4))) short s4v;      // 4 bf16 = 2 VGPRs
typedef __attribute__((ext_vector_type(4))) float floatx4;

#define B_ 2
#define S_ 2048
#define D_ 1024
#define H_ 16
#define DK_ 64
#define M_ 4096
#define HEADELEMS 131072   // S_*DK_ per (b,h)
#define TILEELEMS 4096     // 64*64 per 64-token tile
#define QSCALE 0.1803368801111204f   // 0.125 * log2(e), folded into Q projection

struct __align__(8) bf16x4 { bf16 x, y, z, w; };

__device__ __forceinline__ floatx4 mfma16(short8 a, short8 b, floatx4 c) {
  return __builtin_amdgcn_mfma_f32_16x16x32_bf16(a, b, c, 0, 0, 0);
}
__device__ __forceinline__ void gl_lds16(const bf16* g, bf16* l) {
  __builtin_amdgcn_global_load_lds((const __attribute__((address_space(1))) void*)g,
                                   (__attribute__((address_space(3))) void*)l, 16, 0, 0);
}
__device__ __forceinline__ float bs2f(short s) {
  bf16 b = *reinterpret_cast<bf16*>(&s);
  return __bfloat162float(b);
}
__device__ __forceinline__ s4v pack4(float p0, float p1, float p2, float p3) {
  union { __hip_bfloat162 h; short2 s; } ua, ub;
  ua.h = __float22bfloat162_rn(make_float2(p0, p1));
  ub.h = __float22bfloat162_rn(make_float2(p2, p3));
  s4v r = {ua.s.x, ua.s.y, ub.s.x, ub.s.y};
  return r;
}

// ---------------- fused fp32->bf16 converts (q,k,v inputs) ----------------
__global__ void convert3(const float* __restrict__ a0, const float* __restrict__ a1,
                         const float* __restrict__ a2, bf16* __restrict__ o0,
                         bf16* __restrict__ o1, bf16* __restrict__ o2, const int n4) {
  const int z = blockIdx.z;
  const float* src = (z == 0) ? a0 : (z == 1) ? a1 : a2;
  bf16* dst = (z == 0) ? o0 : (z == 1) ? o1 : o2;
  const int i = blockIdx.x * blockDim.x + threadIdx.x;
  if (i >= n4) return;
  float4 v = ((const float4*)src)[i];
  bf16x4 o = { __float2bfloat16(v.x), __float2bfloat16(v.y),
               __float2bfloat16(v.z), __float2bfloat16(v.w) };
  ((bf16x4*)dst)[i] = o;
}

// ---------------- fused weight transposes fp32 [R][C] -> bf16 [C][R] ----------------
__global__ void transpose4(const float* __restrict__ s0, const float* __restrict__ s1,
                           const float* __restrict__ s2, const float* __restrict__ s3,
                           bf16* __restrict__ d0, bf16* __restrict__ d1,
                           bf16* __restrict__ d2, bf16* __restrict__ d3) {
  const int z = blockIdx.z;
  const float* src = (z == 0) ? s0 : (z == 1) ? s1 : (z == 2) ? s2 : s3;
  bf16* dst = (z == 0) ? d0 : (z == 1) ? d1 : (z == 2) ? d2 : d3;
  __shared__ bf16 tile[64][66];
  const int r0 = blockIdx.y * 64, c0 = blockIdx.x * 64;
  const int tid = threadIdx.x;
  const int lr = tid >> 4;
  const int lc4 = (tid & 15) * 4;
#pragma unroll
  for (int i = 0; i < 4; ++i) {
    const int r = lr + i * 16;
    float4 v = *(const float4*)(src + (size_t)(r0 + r) * D_ + c0 + lc4);
    tile[r][lc4 + 0] = __float2bfloat16(v.x);
    tile[r][lc4 + 1] = __float2bfloat16(v.y);
    tile[r][lc4 + 2] = __float2bfloat16(v.z);
    tile[r][lc4 + 3] = __float2bfloat16(v.w);
  }
  __syncthreads();
  const int orr = tid & 63;
  const int oc0 = tid >> 6;
#pragma unroll
  for (int j = 0; j < 16; ++j) {
    const int oc = oc0 + j * 4;
    dst[(size_t)(c0 + oc) * D_ + r0 + orr] = tile[orr][oc];
  }
}

// ---------------- padding-mask dtype detector ----------------
__global__ void detect_mask(const unsigned int* __restrict__ p, int* __restrict__ flag) {
  __shared__ int sbyte;
  if (threadIdx.x == 0) sbyte = 0;
  __syncthreads();
  for (int i = threadIdx.x; i < (B_ * S_) / 4; i += 256) {
    const unsigned int v = p[i];
    if (((v & 0xFEFEFEFEu) == 0u) && ((v & 0xFFFFFF00u) != 0u)) sbyte = 1;
  }
  __syncthreads();
  if (threadIdx.x == 0) *flag = sbyte;
}

// ---------------- bf16 GEMM, C = A[M,K] * W[N,K]^T + bias ----------------
// mode 0: bf16 out, Q/K fragment-swizzled per-head tiles (LDS-bounced coalesced stores)
// mode 1: bf16 out, V^T fragment-swizzled per-head tiles (LDS-bounced coalesced stores)
// mode 2: fp32 out, plain [M][N]
// sc applied (on top of bias) only for z==0 outputs (Q scale folding).
template<int MT>
__global__ __launch_bounds__(256, 2) void gemm_k(
    const bf16* __restrict__ A0, const bf16* __restrict__ A1, const bf16* __restrict__ A2,
    const bf16* __restrict__ W0, const bf16* __restrict__ W1, const bf16* __restrict__ W2,
    const float* __restrict__ b0, const float* __restrict__ b1, const float* __restrict__ b2,
    void* __restrict__ O0, void* __restrict__ O1, void* __restrict__ O2,
    const int mode01, const int Kd, const float sc)
{
  __shared__ __align__(16) bf16 sh[(MT + 128) * 32];   // As | Bs, contiguous
  bf16* As = sh;
  bf16* Bs = sh + MT * 32;
  const int z = blockIdx.z;
  const bf16* A = (z == 0) ? A0 : (z == 1) ? A1 : A2;
  const bf16* W = (z == 0) ? W0 : (z == 1) ? W1 : W2;
  const float* bias = (z == 0) ? b0 : (z == 1) ? b1 : b2;
  void* Cout = (z == 0) ? O0 : (z == 1) ? O1 : O2;
  const int mode = (z == 2) ? 1 : mode01;
  const float scz = (z == 0) ? sc : 1.f;

  constexpr int MI = MT / 32;
  const int tid = threadIdx.x;
  const int wave = tid >> 6, lane = tid & 63;
  const int quad = lane >> 4, lc = lane & 15;
  const int wm = (wave >> 1) * (MT / 2), wn = (wave & 1) * 64;
  const int m0 = blockIdx.y * MT, n0 = blockIdx.x * 128;

  const floatx4 zero4 = {0.f, 0.f, 0.f, 0.f};
  floatx4 acc[MI][4];
#pragma unroll
  for (int mi = 0; mi < MI; ++mi)
#pragma unroll
    for (int ni = 0; ni < 4; ++ni) acc[mi][ni] = zero4;

  const int ldr = lane >> 2;
  const int ldc = (lane & 3) * 8;
  const bf16* Ag = A + (size_t)(m0 + wave * (MT / 4) + ldr) * Kd + ldc;
  const bf16* Bg = W + (size_t)(n0 + wave * 32 + ldr) * Kd + ldc;
  bf16* As0 = As + wave * (MT / 4) * 32;
  bf16* Bs0 = Bs + wave * 32 * 32;

  for (int k0 = 0; k0 < Kd; k0 += 32) {
    gl_lds16(Ag + k0, As0);
    if (MT == 128) gl_lds16(Ag + k0 + (size_t)16 * Kd, As0 + 16 * 32);
    gl_lds16(Bg + k0, Bs0);
    gl_lds16(Bg + k0 + (size_t)16 * Kd, Bs0 + 16 * 32);
    __syncthreads();

    short8 af[MI], bfr[4];
#pragma unroll
    for (int i = 0; i < MI; ++i)
      af[i] = *(const short8*)(As + (wm + i * 16 + lc) * 32 + quad * 8);
#pragma unroll
    for (int i = 0; i < 4; ++i)
      bfr[i] = *(const short8*)(Bs + (wn + i * 16 + lc) * 32 + quad * 8);
#pragma unroll
    for (int mi = 0; mi < MI; ++mi)
#pragma unroll
      for (int ni = 0; ni < 4; ++ni)
        acc[mi][ni] = mfma16(af[mi], bfr[ni], acc[mi][ni]);
    __syncthreads();
  }

  if (mode == 2) {
    float* out = (float*)Cout;
#pragma unroll
    for (int mi = 0; mi < MI; ++mi)
#pragma unroll
      for (int ni = 0; ni < 4; ++ni) {
        const int col = n0 + wn + ni * 16 + lc;
        const float bv = bias[col];
        const int rbase = m0 + wm + mi * 16 + quad * 4;
#pragma unroll
        for (int r = 0; r < 4; ++r)
          out[(size_t)(rbase + r) * D_ + col] = acc[mi][ni][r] + bv;
      }
  } else {
    // LDS-bounce: this wave's 64x64 quadrant == one (T, head) swizzled tile.
    bf16* pool = sh + wave * 2048;
    float bvs[4];
#pragma unroll
    for (int ni = 0; ni < 4; ++ni) bvs[ni] = bias[n0 + wn + ni * 16 + lc];
    const int hcol = (n0 + wn) >> 6;
    const int mglob = m0 + wm;
    bf16* outb = (bf16*)Cout + (size_t)((mglob >> 11) * H_ + hcol) * HEADELEMS
               + (size_t)((mglob & (S_ - 1)) >> 6) * TILEELEMS;
#pragma unroll
    for (int half = 0; half < MI / 2; ++half) {
#pragma unroll
      for (int mi2 = 0; mi2 < 2; ++mi2) {
        const int mi = half * 2 + mi2;
#pragma unroll
        for (int ni = 0; ni < 4; ++ni) {
          const int dkl = ni * 16 + lc;
#pragma unroll
          for (int r = 0; r < 4; ++r) {
            const float v = (acc[mi][ni][r] + bvs[ni]) * scz;
            int idx;
            if (mode == 0) {
              const int c = (mi2 * 2 + (dkl >> 5)) * 64 + ((dkl >> 3) & 3) * 16 + quad * 4 + r;
              idx = c * 8 + (dkl & 7);
            } else {
              const int c = (mi2 * 4 + (dkl >> 4)) * 64 + quad * 16 + (dkl & 15);
              idx = c * 4 + r;
            }
            pool[idx] = __float2bfloat16(v);
          }
        }
      }
#pragma unroll
      for (int t = 0; t < 4; ++t) {
        const short8 vv = *(const short8*)(pool + t * 512 + lane * 8);
        *(short8*)(outb + half * 2048 + t * 512 + lane * 8) = vv;
      }
    }
  }
}

// ---------------- V suffix sums ----------------
__global__ void suf_kernel(const bf16* __restrict__ vp, float* __restrict__ suf) {
  __shared__ float ts[32 * 64];
  const int bhid = blockIdx.x;
  const bf16* vb = vp + (size_t)bhid * HEADELEMS;
  const int tid = threadIdx.x;
  const int dk = tid & 63, g = tid >> 6;
  const int dkt = dk >> 4, lck = dk & 15;
  for (int T = g * 8; T < g * 8 + 8; ++T) {
    float sum = 0.f;
#pragma unroll
    for (int w = 0; w < 4; ++w)
#pragma unroll
      for (int qd = 0; qd < 4; ++qd) {
        const s4v x = *(const s4v*)(vb + (size_t)T * TILEELEMS
                                    + (size_t)(((w * 4 + dkt) * 64 + qd * 16 + lck)) * 4);
        sum += bs2f(x[0]) + bs2f(x[1]) + bs2f(x[2]) + bs2f(x[3]);
      }
    ts[T * 64 + dk] = sum;
  }
  __syncthreads();
  if (g == 0) {
    float run = 0.f;
    float* out = suf + (size_t)bhid * (33 * 64);
    out[32 * 64 + dk] = 0.f;
    for (int T = 31; T >= 0; --T) { run += ts[T * 64 + dk]; out[T * 64 + dk] = run; }
  }
}

// ---------------- fused attention ----------------
__device__ __forceinline__ void load_pad(const void* pad, int bytemode, int idx, bool pm[4]) {
  if (bytemode) {
    const uchar4 u = *(const uchar4*)((const unsigned char*)pad + idx);
    pm[0] = u.x != 0; pm[1] = u.y != 0; pm[2] = u.z != 0; pm[3] = u.w != 0;
  } else {
    const int4 u = *(const int4*)((const int*)pad + idx);
    pm[0] = u.x != 0; pm[1] = u.y != 0; pm[2] = u.z != 0; pm[3] = u.w != 0;
  }
}

// S^T = K*Q^T for one 64-key tile (wave owns 16-key strip); mask+exp -> pf (P^T, B-frag-ready)
__device__ __forceinline__ void qk_tile(const short8 ak0, const short8 ak1,
                                        const short8 (&qf)[4][2],
                                        const bool pm[4], float (&lacc)[4], s4v (&pf)[4],
                                        const int w, const int quad, const int lc,
                                        const bool diag) {
  const floatx4 z4 = {0.f, 0.f, 0.f, 0.f};
  const short ONE = (short)0x3F80;
#pragma unroll
  for (int qt = 0; qt < 4; ++qt) {
    if (diag && w > qt) {          // strictly-upper 16x16 subtile: all masked -> p = 1
      s4v o1 = {ONE, ONE, ONE, ONE};
      pf[qt] = o1;
      lacc[qt] += 4.f;
      continue;
    }
    floatx4 s = mfma16(ak0, qf[qt][0], z4);
    s = mfma16(ak1, qf[qt][1], s);
    float pv[4];
#pragma unroll
    for (int r = 0; r < 4; ++r) {
      bool m = pm[r];
      if (diag && w == qt) m = m || (quad * 4 + r > lc);
      pv[r] = exp2f(m ? 0.f : s[r]);
      lacc[qt] += pv[r];
    }
    pf[qt] = pack4(pv[0], pv[1], pv[2], pv[3]);
  }
}

// 256-thread block = 4 strip-waves, one q-tile. Single-buffered 33KB LDS -> 4 blocks/CU.
// 1D grid of 1024: lin&7 = XCD slot; complementary qt ordering balances depth per CU.
// Epilogue assembles the 64x64 bf16 output tile in LDS, stores full 128B lines.
__global__ __launch_bounds__(256, 4) void attn_kernel(
    const bf16* __restrict__ qp, const bf16* __restrict__ kp,
    const bf16* __restrict__ vp, const float* __restrict__ suf,
    const void* __restrict__ pad, const int* __restrict__ flag,
    bf16* __restrict__ oa)
{
  __shared__ __align__(16) bf16 smem[16384];   // main: K0|K1|V0|V1; epi: fbuf[0,8192) obuf[10240,14848)
  __shared__ float lbuf[256];

  const int lin = blockIdx.x;
  const int xcd = lin & 7;
  const int i2 = lin >> 3;             // 0..127
  const int grp = i2 >> 5;             // 0..3
  const int r5 = i2 & 31;
  const int bh = xcd + 8 * grp;
  const int myqt = (grp & 1) ? r5 : (31 - r5);
  const int b = bh >> 4, h = bh & 15;

  const int mynt = myqt + 1;
  const int mynp = (mynt + 1) >> 1;
  const int tid = threadIdx.x;
  const int w = tid >> 6, lane = tid & 63, quad = lane >> 4, lc = lane & 15;
  const int bytemode = *flag;
  const int padbase = b * S_;
  const bf16* kb = kp + (size_t)bh * HEADELEMS;
  const bf16* vb = vp + (size_t)bh * HEADELEMS;

  // Q fragments for this block's q-tile (B-operand for S^T = K*Q^T)
  const bf16* qb = qp + (size_t)bh * HEADELEMS + (size_t)myqt * TILEELEMS;
  short8 qf[4][2];
#pragma unroll
  for (int qt = 0; qt < 4; ++qt)
#pragma unroll
    for (int hh = 0; hh < 2; ++hh)
      qf[qt][hh] = *(const short8*)(qb + (size_t)((qt * 2 + hh) * 64 + lane) * 8);

  const floatx4 zero4 = {0.f, 0.f, 0.f, 0.f};
  floatx4 oacc[4][4];                            // [dkt][qt]
#pragma unroll
  for (int i = 0; i < 4; ++i)
#pragma unroll
    for (int jj = 0; jj < 4; ++jj) oacc[i][jj] = zero4;
  float lacc[4] = {0.f, 0.f, 0.f, 0.f};

  for (int p = 0; p < mynp; ++p) {
    const size_t t0 = (size_t)(2 * p) * TILEELEMS;
    const size_t t1 = t0 + TILEELEMS;
#pragma unroll
    for (int i = 0; i < 2; ++i) {
      const size_t co = (size_t)((w * 2 + i) * 64 + lane) * 8;
      const int so = (w * 2 + i) * 512;
      gl_lds16(kb + t0 + co, smem + so);
      gl_lds16(kb + t1 + co, smem + 4096 + so);
      gl_lds16(vb + t0 + co, smem + 8192 + so);
      gl_lds16(vb + t1 + co, smem + 12288 + so);
    }
    __syncthreads();

    const int T0 = 2 * p, T1 = 2 * p + 1;
    const short8 ak00 = *(const short8*)(smem + (size_t)(w * 128 + lane) * 8);
    const short8 ak01 = *(const short8*)(smem + (size_t)(w * 128 + 64 + lane) * 8);
    const short8 ak10 = *(const short8*)(smem + 4096 + (size_t)(w * 128 + lane) * 8);
    const short8 ak11 = *(const short8*)(smem + 4096 + (size_t)(w * 128 + 64 + lane) * 8);

    bool pm[4];
    s4v pf0[4], pf1[4];
    load_pad(pad, bytemode, padbase + T0 * 64 + w * 16 + quad * 4, pm);
    qk_tile(ak00, ak01, qf, pm, lacc, pf0, w, quad, lc, T0 == mynt - 1);
    if (T1 < mynt) {
      load_pad(pad, bytemode, padbase + T1 * 64 + w * 16 + quad * 4, pm);
      qk_tile(ak10, ak11, qf, pm, lacc, pf1, w, quad, lc, T1 == mynt - 1);
    } else {
      const s4v zz = {0, 0, 0, 0};
#pragma unroll
      for (int qt = 0; qt < 4; ++qt) pf1[qt] = zz;   // phantom: covered by suffix sums
    }

    short8 pB[4];
#pragma unroll
    for (int qt = 0; qt < 4; ++qt)
      pB[qt] = __builtin_shufflevector(pf0[qt], pf1[qt], 0, 1, 2, 3, 4, 5, 6, 7);
#pragma unroll
    for (int dkt = 0; dkt < 4; ++dkt) {
      const s4v a0 = *(const s4v*)(smem + 8192  + (size_t)((w * 4 + dkt) * 64 + lane) * 4);
      const s4v a1 = *(const s4v*)(smem + 12288 + (size_t)((w * 4 + dkt) * 64 + lane) * 4);
      const short8 av = __builtin_shufflevector(a0, a1, 0, 1, 2, 3, 4, 5, 6, 7);
#pragma unroll
      for (int qt = 0; qt < 4; ++qt)
        oacc[dkt][qt] = mfma16(av, pB[qt], oacc[dkt][qt]);
    }
    __syncthreads();                             // before next-iter staging overwrites
  }

  // ---- epilogue: cross-strip reduction -> LDS out-tile -> coalesced full-line stores ----
#pragma unroll
  for (int qt = 0; qt < 4; ++qt) {
    float v = lacc[qt];
    v += __shfl_xor(v, 16);
    v += __shfl_xor(v, 32);
    if (quad == 0) lbuf[w * 64 + qt * 16 + lc] = v;
  }
  __syncthreads();
  float* fbuf = (float*)smem;                    // 16 KB region (4096 floats)
  bf16* obuf = smem + 10240;                     // 64 rows x stride 72 = 9216 B
  float ls = lbuf[0 * 64 + w * 16 + lc] + lbuf[1 * 64 + w * 16 + lc]
           + lbuf[2 * 64 + w * 16 + lc] + lbuf[3 * 64 + w * 16 + lc];
  ls += (float)(S_ - mynt * 64);                 // keys past diagonal tile: weight 1 each
  const float linv = 1.f / ls;
  const float* sufp = suf + (size_t)bh * (33 * 64) + mynt * 64;

#pragma unroll
  for (int dktG = 0; dktG < 4; ++dktG) {
    // each strip-wave writes its 4 qt-tiles for this dkt group
#pragma unroll
    for (int qt = 0; qt < 4; ++qt) {
      const floatx4 a = oacc[dktG][qt];
      float* dst = fbuf + (w * 4 + qt) * 256 + lc;
#pragma unroll
      for (int r = 0; r < 4; ++r) dst[(quad * 4 + r) * 16] = a[r];
    }
    __syncthreads();
    // wave w reduces tiles qt == w across the 4 strips
    const float4 sv4 = *(const float4*)(sufp + dktG * 16 + quad * 4);
    float v[4];
#pragma unroll
    for (int r = 0; r < 4; ++r) {
      const int e = (quad * 4 + r) * 16 + lc;
      v[r] = fbuf[(0 * 4 + w) * 256 + e] + fbuf[(1 * 4 + w) * 256 + e]
           + fbuf[(2 * 4 + w) * 256 + e] + fbuf[(3 * 4 + w) * 256 + e];
    }
    v[0] = (v[0] + sv4.x) * linv; v[1] = (v[1] + sv4.y) * linv;
    v[2] = (v[2] + sv4.z) * linv; v[3] = (v[3] + sv4.w) * linv;
    bf16x4 pk = { __float2bfloat16(v[0]), __float2bfloat16(v[1]),
                  __float2bfloat16(v[2]), __float2bfloat16(v[3]) };
    *(bf16x4*)(obuf + (w * 16 + lc) * 72 + dktG * 16 + quad * 4) = pk;
    __syncthreads();
  }

  // store: 2 instructions, each = 8 rows x 128B full lines
  const size_t obase = (size_t)(b * S_ + myqt * 64) * D_ + h * 64;
#pragma unroll
  for (int it = 0; it < 2; ++it) {
    const int idx = it * 256 + tid;
    const int row = idx >> 3, c8 = (idx & 7) * 8;
    const short8 vv = *(const short8*)(obuf + row * 72 + c8);
    *(short8*)(oa + obase + (size_t)row * D_ + c8) = vv;
  }
}

extern "C" void kernel_launch(void* const* d_in, const int* in_sizes, int n_in,
                              void* d_out, int out_size, void* d_ws, size_t ws_size,
                              hipStream_t stream) {
  (void)in_sizes; (void)n_in; (void)out_size; (void)ws_size;
  const float* q_in = (const float*)d_in[0];
  const float* k_in = (const float*)d_in[1];
  const float* v_in = (const float*)d_in[2];
  const void*  pmask = d_in[3];
  const float* Wq = (const float*)d_in[4];
  const float* bq = (const float*)d_in[5];
  const float* Wk = (const float*)d_in[6];
  const float* bk = (const float*)d_in[7];
  const float* Wv = (const float*)d_in[8];
  const float* bv = (const float*)d_in[9];
  const float* Wo = (const float*)d_in[10];
  const float* bo = (const float*)d_in[11];

  char* ws = (char*)d_ws;
  bf16* xq  = (bf16*)(ws + 0);
  bf16* xk  = (bf16*)(ws + 8388608);
  bf16* xv  = (bf16*)(ws + 16777216);
  bf16* wqt = (bf16*)(ws + 25165824);
  bf16* wkt = (bf16*)(ws + 27262976);
  bf16* wvt = (bf16*)(ws + 29360128);
  bf16* wot = (bf16*)(ws + 31457280);
  bf16* qpp = (bf16*)(ws + 33554432);
  bf16* kpp = (bf16*)(ws + 41943040);
  bf16* vpp = (bf16*)(ws + 50331648);
  float* suf = (float*)(ws + 25165824);   // overlays wqt (dead after projections)
  int*  flg = (int*)(ws + 58720256);
  bf16* oa  = xq;

  const int n4 = (M_ * D_) / 4;
  convert3<<<dim3(4096, 1, 3), 256, 0, stream>>>(q_in, k_in, v_in, xq, xk, xv, n4);
  transpose4<<<dim3(16, 16, 4), 256, 0, stream>>>(Wq, Wk, Wv, Wo, wqt, wkt, wvt, wot);
  detect_mask<<<1, 256, 0, stream>>>((const unsigned int*)pmask, flg);

  gemm_k<128><<<dim3(8, 32, 3), 256, 0, stream>>>(xq, xk, xv, wqt, wkt, wvt,
                                                  bq, bk, bv, qpp, kpp, vpp, 0, D_, QSCALE);
  suf_kernel<<<32, 256, 0, stream>>>(vpp, suf);

  attn_kernel<<<1024, 256, 0, stream>>>(qpp, kpp, vpp, suf, pmask, flg, oa);

  gemm_k<64><<<dim3(8, 64, 1), 256, 0, stream>>>(oa, oa, oa, wot, wot, wot,
                                                 bo, bo, bo, d_out, d_out, d_out, 2, D_, 1.f);
}

// Round 6
// 277.011 us; speedup vs baseline: 1.1399x; 1.1399x over previous
//
#include <hip/hip_runtime.h>
#include <hip/hip_bf16.h>
#include <cstdint>
#include <cstddef>

typedef __hip_bfloat16 bf16;
typedef __attribute__((ext_vector_type(8))) short short8;   // 8 bf16 = 4 VGPRs
typedef __attribute__((ext_vector_type(4))) short s4v;      // 4 bf16 = 2 VGPRs
typedef __attribute__((ext_vector_type(4))) float floatx4;

#define B_ 2
#define S_ 2048
#define D_ 1024
#define H_ 16
#define DK_ 64
#define M_ 4096
#define HEADELEMS 131072   // S_*DK_ per (b,h)
#define TILEELEMS 4096     // 64*64 per 64-token tile
#define QSCALE 0.1803368801111204f   // 0.125 * log2(e), folded into Q projection

struct __align__(8) bf16x4 { bf16 x, y, z, w; };

__device__ __forceinline__ floatx4 mfma16(short8 a, short8 b, floatx4 c) {
  return __builtin_amdgcn_mfma_f32_16x16x32_bf16(a, b, c, 0, 0, 0);
}
__device__ __forceinline__ void gl_lds16(const bf16* g, bf16* l) {
  __builtin_amdgcn_global_load_lds((const __attribute__((address_space(1))) void*)g,
                                   (__attribute__((address_space(3))) void*)l, 16, 0, 0);
}
__device__ __forceinline__ float bs2f(short s) {
  bf16 b = *reinterpret_cast<bf16*>(&s);
  return __bfloat162float(b);
}
__device__ __forceinline__ s4v pack4(float p0, float p1, float p2, float p3) {
  union { __hip_bfloat162 h; short2 s; } ua, ub;
  ua.h = __float22bfloat162_rn(make_float2(p0, p1));
  ub.h = __float22bfloat162_rn(make_float2(p2, p3));
  s4v r = {ua.s.x, ua.s.y, ub.s.x, ub.s.y};
  return r;
}

// ---------------- fused fp32->bf16 converts (q,k,v inputs) ----------------
__global__ void convert3(const float* __restrict__ a0, const float* __restrict__ a1,
                         const float* __restrict__ a2, bf16* __restrict__ o0,
                         bf16* __restrict__ o1, bf16* __restrict__ o2, const int n4) {
  const int z = blockIdx.z;
  const float* src = (z == 0) ? a0 : (z == 1) ? a1 : a2;
  bf16* dst = (z == 0) ? o0 : (z == 1) ? o1 : o2;
  const int i = blockIdx.x * blockDim.x + threadIdx.x;
  if (i >= n4) return;
  float4 v = ((const float4*)src)[i];
  bf16x4 o = { __float2bfloat16(v.x), __float2bfloat16(v.y),
               __float2bfloat16(v.z), __float2bfloat16(v.w) };
  ((bf16x4*)dst)[i] = o;
}

// ---------------- fused weight transposes fp32 [R][C] -> bf16 [C][R] ----------------
__global__ void transpose4(const float* __restrict__ s0, const float* __restrict__ s1,
                           const float* __restrict__ s2, const float* __restrict__ s3,
                           bf16* __restrict__ d0, bf16* __restrict__ d1,
                           bf16* __restrict__ d2, bf16* __restrict__ d3) {
  const int z = blockIdx.z;
  const float* src = (z == 0) ? s0 : (z == 1) ? s1 : (z == 2) ? s2 : s3;
  bf16* dst = (z == 0) ? d0 : (z == 1) ? d1 : (z == 2) ? d2 : d3;
  __shared__ bf16 tile[64][66];
  const int r0 = blockIdx.y * 64, c0 = blockIdx.x * 64;
  const int tid = threadIdx.x;
  const int lr = tid >> 4;
  const int lc4 = (tid & 15) * 4;
#pragma unroll
  for (int i = 0; i < 4; ++i) {
    const int r = lr + i * 16;
    float4 v = *(const float4*)(src + (size_t)(r0 + r) * D_ + c0 + lc4);
    tile[r][lc4 + 0] = __float2bfloat16(v.x);
    tile[r][lc4 + 1] = __float2bfloat16(v.y);
    tile[r][lc4 + 2] = __float2bfloat16(v.z);
    tile[r][lc4 + 3] = __float2bfloat16(v.w);
  }
  __syncthreads();
  const int orr = tid & 63;
  const int oc0 = tid >> 6;
#pragma unroll
  for (int j = 0; j < 16; ++j) {
    const int oc = oc0 + j * 4;
    dst[(size_t)(c0 + oc) * D_ + r0 + orr] = tile[orr][oc];
  }
}

// ---------------- padding-mask dtype detector ----------------
__global__ void detect_mask(const unsigned int* __restrict__ p, int* __restrict__ flag) {
  __shared__ int sbyte;
  if (threadIdx.x == 0) sbyte = 0;
  __syncthreads();
  for (int i = threadIdx.x; i < (B_ * S_) / 4; i += 256) {
    const unsigned int v = p[i];
    if (((v & 0xFEFEFEFEu) == 0u) && ((v & 0xFFFFFF00u) != 0u)) sbyte = 1;
  }
  __syncthreads();
  if (threadIdx.x == 0) *flag = sbyte;
}

// ---------------- bf16 GEMM, C = A[M,K] * W[N,K]^T + bias ----------------
// mode 0: bf16 out, Q/K fragment-swizzled per-head tiles (LDS-bounced coalesced stores)
// mode 1: bf16 out, V^T fragment-swizzled per-head tiles (LDS-bounced coalesced stores)
// mode 2: fp32 out, plain [M][N]
template<int MT>
__global__ __launch_bounds__(256, 2) void gemm_k(
    const bf16* __restrict__ A0, const bf16* __restrict__ A1, const bf16* __restrict__ A2,
    const bf16* __restrict__ W0, const bf16* __restrict__ W1, const bf16* __restrict__ W2,
    const float* __restrict__ b0, const float* __restrict__ b1, const float* __restrict__ b2,
    void* __restrict__ O0, void* __restrict__ O1, void* __restrict__ O2,
    const int mode01, const int Kd, const float sc)
{
  __shared__ __align__(16) bf16 sh[(MT + 128) * 32];   // As | Bs, contiguous
  bf16* As = sh;
  bf16* Bs = sh + MT * 32;
  const int z = blockIdx.z;
  const bf16* A = (z == 0) ? A0 : (z == 1) ? A1 : A2;
  const bf16* W = (z == 0) ? W0 : (z == 1) ? W1 : W2;
  const float* bias = (z == 0) ? b0 : (z == 1) ? b1 : b2;
  void* Cout = (z == 0) ? O0 : (z == 1) ? O1 : O2;
  const int mode = (z == 2) ? 1 : mode01;
  const float scz = (z == 0) ? sc : 1.f;

  constexpr int MI = MT / 32;
  const int tid = threadIdx.x;
  const int wave = tid >> 6, lane = tid & 63;
  const int quad = lane >> 4, lc = lane & 15;
  const int wm = (wave >> 1) * (MT / 2), wn = (wave & 1) * 64;
  const int m0 = blockIdx.y * MT, n0 = blockIdx.x * 128;

  const floatx4 zero4 = {0.f, 0.f, 0.f, 0.f};
  floatx4 acc[MI][4];
#pragma unroll
  for (int mi = 0; mi < MI; ++mi)
#pragma unroll
    for (int ni = 0; ni < 4; ++ni) acc[mi][ni] = zero4;

  const int ldr = lane >> 2;
  const int ldc = (lane & 3) * 8;
  const bf16* Ag = A + (size_t)(m0 + wave * (MT / 4) + ldr) * Kd + ldc;
  const bf16* Bg = W + (size_t)(n0 + wave * 32 + ldr) * Kd + ldc;
  bf16* As0 = As + wave * (MT / 4) * 32;
  bf16* Bs0 = Bs + wave * 32 * 32;

  for (int k0 = 0; k0 < Kd; k0 += 32) {
    gl_lds16(Ag + k0, As0);
    if (MT == 128) gl_lds16(Ag + k0 + (size_t)16 * Kd, As0 + 16 * 32);
    gl_lds16(Bg + k0, Bs0);
    gl_lds16(Bg + k0 + (size_t)16 * Kd, Bs0 + 16 * 32);
    __syncthreads();

    short8 af[MI], bfr[4];
#pragma unroll
    for (int i = 0; i < MI; ++i)
      af[i] = *(const short8*)(As + (wm + i * 16 + lc) * 32 + quad * 8);
#pragma unroll
    for (int i = 0; i < 4; ++i)
      bfr[i] = *(const short8*)(Bs + (wn + i * 16 + lc) * 32 + quad * 8);
#pragma unroll
    for (int mi = 0; mi < MI; ++mi)
#pragma unroll
      for (int ni = 0; ni < 4; ++ni)
        acc[mi][ni] = mfma16(af[mi], bfr[ni], acc[mi][ni]);
    __syncthreads();
  }

  if (mode == 2) {
    float* out = (float*)Cout;
#pragma unroll
    for (int mi = 0; mi < MI; ++mi)
#pragma unroll
      for (int ni = 0; ni < 4; ++ni) {
        const int col = n0 + wn + ni * 16 + lc;
        const float bv = bias[col];
        const int rbase = m0 + wm + mi * 16 + quad * 4;
#pragma unroll
        for (int r = 0; r < 4; ++r)
          out[(size_t)(rbase + r) * D_ + col] = acc[mi][ni][r] + bv;
      }
  } else {
    // LDS-bounce: this wave's 64x64 quadrant == one (T, head) swizzled tile.
    bf16* pool = sh + wave * 2048;
    float bvs[4];
#pragma unroll
    for (int ni = 0; ni < 4; ++ni) bvs[ni] = bias[n0 + wn + ni * 16 + lc];
    const int hcol = (n0 + wn) >> 6;
    const int mglob = m0 + wm;
    bf16* outb = (bf16*)Cout + (size_t)((mglob >> 11) * H_ + hcol) * HEADELEMS
               + (size_t)((mglob & (S_ - 1)) >> 6) * TILEELEMS;
#pragma unroll
    for (int half = 0; half < MI / 2; ++half) {
#pragma unroll
      for (int mi2 = 0; mi2 < 2; ++mi2) {
        const int mi = half * 2 + mi2;
#pragma unroll
        for (int ni = 0; ni < 4; ++ni) {
          const int dkl = ni * 16 + lc;
#pragma unroll
          for (int r = 0; r < 4; ++r) {
            const float v = (acc[mi][ni][r] + bvs[ni]) * scz;
            int idx;
            if (mode == 0) {
              const int c = (mi2 * 2 + (dkl >> 5)) * 64 + ((dkl >> 3) & 3) * 16 + quad * 4 + r;
              idx = c * 8 + (dkl & 7);
            } else {
              const int c = (mi2 * 4 + (dkl >> 4)) * 64 + quad * 16 + (dkl & 15);
              idx = c * 4 + r;
            }
            pool[idx] = __float2bfloat16(v);
          }
        }
      }
#pragma unroll
      for (int t = 0; t < 4; ++t) {
        const short8 vv = *(const short8*)(pool + t * 512 + lane * 8);
        *(short8*)(outb + half * 2048 + t * 512 + lane * 8) = vv;
      }
    }
  }
}

// ---------------- V suffix sums ----------------
__global__ void suf_kernel(const bf16* __restrict__ vp, float* __restrict__ suf) {
  __shared__ float ts[32 * 64];
  const int bhid = blockIdx.x;
  const bf16* vb = vp + (size_t)bhid * HEADELEMS;
  const int tid = threadIdx.x;
  const int dk = tid & 63, g = tid >> 6;
  const int dkt = dk >> 4, lck = dk & 15;
  for (int T = g * 8; T < g * 8 + 8; ++T) {
    float sum = 0.f;
#pragma unroll
    for (int w = 0; w < 4; ++w)
#pragma unroll
      for (int qd = 0; qd < 4; ++qd) {
        const s4v x = *(const s4v*)(vb + (size_t)T * TILEELEMS
                                    + (size_t)(((w * 4 + dkt) * 64 + qd * 16 + lck)) * 4);
        sum += bs2f(x[0]) + bs2f(x[1]) + bs2f(x[2]) + bs2f(x[3]);
      }
    ts[T * 64 + dk] = sum;
  }
  __syncthreads();
  if (g == 0) {
    float run = 0.f;
    float* out = suf + (size_t)bhid * (33 * 64);
    out[32 * 64 + dk] = 0.f;
    for (int T = 31; T >= 0; --T) { run += ts[T * 64 + dk]; out[T * 64 + dk] = run; }
  }
}

// ---------------- fused attention ----------------
__device__ __forceinline__ void load_pad(const void* pad, int bytemode, int idx, bool pm[4]) {
  if (bytemode) {
    const uchar4 u = *(const uchar4*)((const unsigned char*)pad + idx);
    pm[0] = u.x != 0; pm[1] = u.y != 0; pm[2] = u.z != 0; pm[3] = u.w != 0;
  } else {
    const int4 u = *(const int4*)((const int*)pad + idx);
    pm[0] = u.x != 0; pm[1] = u.y != 0; pm[2] = u.z != 0; pm[3] = u.w != 0;
  }
}

// S^T = K*Q^T for one 64-key tile (wave owns 16-key strip); mask+exp -> pf (P^T, B-frag-ready)
// Q pre-scaled by 0.125*log2(e) at projection time.
__device__ __forceinline__ void qk_tile(const short8 ak0, const short8 ak1,
                                        const short8 (&qf)[4][2],
                                        const bool pm[4], float (&lacc)[4], s4v (&pf)[4],
                                        const int ws, const int quad, const int lc,
                                        const bool diag) {
  const floatx4 z4 = {0.f, 0.f, 0.f, 0.f};
  const short ONE = (short)0x3F80;
#pragma unroll
  for (int qt = 0; qt < 4; ++qt) {
    if (diag && ws > qt) {          // strictly-upper 16x16 subtile: all masked -> p = 1
      s4v o1 = {ONE, ONE, ONE, ONE};
      pf[qt] = o1;
      lacc[qt] += 4.f;
      continue;
    }
    floatx4 s = mfma16(ak0, qf[qt][0], z4);
    s = mfma16(ak1, qf[qt][1], s);
    float pv[4];
#pragma unroll
    for (int r = 0; r < 4; ++r) {
      bool m = pm[r];
      if (diag && ws == qt) m = m || (quad * 4 + r > lc);
      pv[r] = exp2f(m ? 0.f : s[r]);
      lacc[qt] += pv[r];
    }
    pf[qt] = pack4(pv[0], pv[1], pv[2], pv[3]);
  }
}

// 512-thread block: waves 0-3 handle q-tile 31-j, waves 4-7 q-tile j (constant 33 tiles/block).
// K/V staged once per key-tile pair (shared by both q-sets), double-buffered.
// Grid 512: lin&7 = XCD = bh&7 (K/V L2-local); grp&2 flips j so a CU's two resident
// blocks have complementary depth. Epilogue: LDS out-tile -> full-128B-line stores.
__global__ __launch_bounds__(512, 4) void attn_kernel(
    const bf16* __restrict__ qp, const bf16* __restrict__ kp,
    const bf16* __restrict__ vp, const float* __restrict__ suf,
    const void* __restrict__ pad, const int* __restrict__ flag,
    bf16* __restrict__ oa)
{
  __shared__ __align__(16) bf16 smem[2][16384];  // per buf: K0,K1,V0,V1 (8KB each)
  __shared__ float lbuf[512];

  const int lin = blockIdx.x;
  const int xcd = lin & 7;
  const int i2 = lin >> 3;           // 0..63
  const int grp = i2 >> 4;           // 0..3
  const int r4 = i2 & 15;
  const int bh = xcd + 8 * grp;
  const int j = (grp & 2) ? (15 - r4) : r4;
  const int b = bh >> 4, h = bh & 15;

  const int tid = threadIdx.x;
  const int w = tid >> 6, lane = tid & 63, quad = lane >> 4, lc = lane & 15;
  const int qset = w >> 2, ws = w & 3;
  const int myqt = (qset == 0) ? (31 - j) : j;
  const int mynt = myqt + 1;
  const int mynp = (mynt + 1) >> 1;
  const int npB  = (32 - j + 1) >> 1;           // loop trip count (big set)
  const int bytemode = *flag;
  const int padbase = b * S_;
  const bf16* kb = kp + (size_t)bh * HEADELEMS;
  const bf16* vb = vp + (size_t)bh * HEADELEMS;

  // Q fragments for this wave's q-tile (B-operand for S^T = K*Q^T)
  const bf16* qb = qp + (size_t)bh * HEADELEMS + (size_t)myqt * TILEELEMS;
  short8 qf[4][2];
#pragma unroll
  for (int qt = 0; qt < 4; ++qt)
#pragma unroll
    for (int hh = 0; hh < 2; ++hh)
      qf[qt][hh] = *(const short8*)(qb + (size_t)((qt * 2 + hh) * 64 + lane) * 8);

  const floatx4 zero4 = {0.f, 0.f, 0.f, 0.f};
  floatx4 oacc[4][4];                            // [dkt][qt]
#pragma unroll
  for (int i = 0; i < 4; ++i)
#pragma unroll
    for (int jj = 0; jj < 4; ++jj) oacc[i][jj] = zero4;
  float lacc[4] = {0.f, 0.f, 0.f, 0.f};

  const size_t co = (size_t)(w * 64 + lane) * 8;   // this wave's 512-elem staging chunk

  // prologue: stage pair 0 into buf 0
  {
    bf16* dst = smem[0];
    gl_lds16(kb + co,             dst + w * 512);
    gl_lds16(kb + TILEELEMS + co, dst + 4096 + w * 512);
    gl_lds16(vb + co,             dst + 8192 + w * 512);
    gl_lds16(vb + TILEELEMS + co, dst + 12288 + w * 512);
  }

  for (int p = 0; p < npB; ++p) {
    __syncthreads();                            // staging of pair p complete
    if (p + 1 < npB) {                          // prefetch pair p+1 (overlaps compute)
      bf16* dst = smem[(p + 1) & 1];
      const size_t t0 = (size_t)(2 * p + 2) * TILEELEMS;
      const size_t t1 = (size_t)(2 * p + 3) * TILEELEMS;
      gl_lds16(kb + t0 + co, dst + w * 512);
      gl_lds16(kb + t1 + co, dst + 4096 + w * 512);
      gl_lds16(vb + t0 + co, dst + 8192 + w * 512);
      gl_lds16(vb + t1 + co, dst + 12288 + w * 512);
    }
    if (p < mynp) {
      const bf16* cur = smem[p & 1];
      const int T0 = 2 * p, T1 = 2 * p + 1;
      const short8 ak00 = *(const short8*)(cur + (size_t)(ws * 128 + lane) * 8);
      const short8 ak01 = *(const short8*)(cur + (size_t)(ws * 128 + 64 + lane) * 8);
      const short8 ak10 = *(const short8*)(cur + 4096 + (size_t)(ws * 128 + lane) * 8);
      const short8 ak11 = *(const short8*)(cur + 4096 + (size_t)(ws * 128 + 64 + lane) * 8);

      bool pm[4];
      s4v pf0[4], pf1[4];
      load_pad(pad, bytemode, padbase + T0 * 64 + ws * 16 + quad * 4, pm);
      qk_tile(ak00, ak01, qf, pm, lacc, pf0, ws, quad, lc, T0 == mynt - 1);
      if (T1 < mynt) {
        load_pad(pad, bytemode, padbase + T1 * 64 + ws * 16 + quad * 4, pm);
        qk_tile(ak10, ak11, qf, pm, lacc, pf1, ws, quad, lc, T1 == mynt - 1);
      } else {
        const s4v zz = {0, 0, 0, 0};
#pragma unroll
        for (int qt = 0; qt < 4; ++qt) pf1[qt] = zz;   // phantom: covered by suffix sums
      }

      short8 pB[4];
#pragma unroll
      for (int qt = 0; qt < 4; ++qt)
        pB[qt] = __builtin_shufflevector(pf0[qt], pf1[qt], 0, 1, 2, 3, 4, 5, 6, 7);
#pragma unroll
      for (int dkt = 0; dkt < 4; ++dkt) {
        const s4v a0 = *(const s4v*)(cur + 8192  + (size_t)((ws * 4 + dkt) * 64 + lane) * 4);
        const s4v a1 = *(const s4v*)(cur + 12288 + (size_t)((ws * 4 + dkt) * 64 + lane) * 4);
        const short8 av = __builtin_shufflevector(a0, a1, 0, 1, 2, 3, 4, 5, 6, 7);
#pragma unroll
        for (int qt = 0; qt < 4; ++qt)
          oacc[dkt][qt] = mfma16(av, pB[qt], oacc[dkt][qt]);
      }
    }
  }

  // ---- epilogue: per-qset reduction -> LDS out-tile -> full-line stores ----
#pragma unroll
  for (int qt = 0; qt < 4; ++qt) {
    float v = lacc[qt];
    v += __shfl_xor(v, 16);
    v += __shfl_xor(v, 32);
    if (quad == 0) lbuf[qset * 256 + ws * 64 + qt * 16 + lc] = v;
  }
  __syncthreads();                               // all staging/compute done; reuse smem
  bf16* qbase = &smem[0][0] + qset * 16384;      // 32KB per qset
  float* fbuf = (float*)qbase;                   // 16KB
  bf16* obuf = qbase + 8192;                     // 64 rows x stride 72 = 9216B
  float ls = lbuf[qset * 256 + 0 * 64 + ws * 16 + lc] + lbuf[qset * 256 + 1 * 64 + ws * 16 + lc]
           + lbuf[qset * 256 + 2 * 64 + ws * 16 + lc] + lbuf[qset * 256 + 3 * 64 + ws * 16 + lc];
  ls += (float)(S_ - mynt * 64);                 // keys past diagonal tile: weight 1 each
  const float linv = 1.f / ls;
  const float* sufp = suf + (size_t)bh * (33 * 64) + mynt * 64;

#pragma unroll
  for (int dktG = 0; dktG < 4; ++dktG) {
#pragma unroll
    for (int qt = 0; qt < 4; ++qt) {
      const floatx4 a = oacc[dktG][qt];
      float* dst = fbuf + (ws * 4 + qt) * 256 + lc;
#pragma unroll
      for (int r = 0; r < 4; ++r) dst[(quad * 4 + r) * 16] = a[r];
    }
    __syncthreads();
    // wave ws reduces tiles qt == ws across the 4 strips
    const float4 sv4 = *(const float4*)(sufp + dktG * 16 + quad * 4);
    float v[4];
#pragma unroll
    for (int r = 0; r < 4; ++r) {
      const int e = (quad * 4 + r) * 16 + lc;
      v[r] = fbuf[(0 * 4 + ws) * 256 + e] + fbuf[(1 * 4 + ws) * 256 + e]
           + fbuf[(2 * 4 + ws) * 256 + e] + fbuf[(3 * 4 + ws) * 256 + e];
    }
    v[0] = (v[0] + sv4.x) * linv; v[1] = (v[1] + sv4.y) * linv;
    v[2] = (v[2] + sv4.z) * linv; v[3] = (v[3] + sv4.w) * linv;
    bf16x4 pk = { __float2bfloat16(v[0]), __float2bfloat16(v[1]),
                  __float2bfloat16(v[2]), __float2bfloat16(v[3]) };
    *(bf16x4*)(obuf + (ws * 16 + lc) * 72 + dktG * 16 + quad * 4) = pk;
    __syncthreads();
  }

  // store this qset's 64x64 tile: 2 instructions x 256 lanes = full 128B lines
  const size_t obase = (size_t)(b * S_ + myqt * 64) * D_ + h * 64;
  const int qtid = tid & 255;
#pragma unroll
  for (int it = 0; it < 2; ++it) {
    const int idx = it * 256 + qtid;
    const int row = idx >> 3, c8 = (idx & 7) * 8;
    const short8 vv = *(const short8*)(obuf + row * 72 + c8);
    *(short8*)(oa + obase + (size_t)row * D_ + c8) = vv;
  }
}

extern "C" void kernel_launch(void* const* d_in, const int* in_sizes, int n_in,
                              void* d_out, int out_size, void* d_ws, size_t ws_size,
                              hipStream_t stream) {
  (void)in_sizes; (void)n_in; (void)out_size; (void)ws_size;
  const float* q_in = (const float*)d_in[0];
  const float* k_in = (const float*)d_in[1];
  const float* v_in = (const float*)d_in[2];
  const void*  pmask = d_in[3];
  const float* Wq = (const float*)d_in[4];
  const float* bq = (const float*)d_in[5];
  const float* Wk = (const float*)d_in[6];
  const float* bk = (const float*)d_in[7];
  const float* Wv = (const float*)d_in[8];
  const float* bv = (const float*)d_in[9];
  const float* Wo = (const float*)d_in[10];
  const float* bo = (const float*)d_in[11];

  char* ws = (char*)d_ws;
  bf16* xq  = (bf16*)(ws + 0);
  bf16* xk  = (bf16*)(ws + 8388608);
  bf16* xv  = (bf16*)(ws + 16777216);
  bf16* wqt = (bf16*)(ws + 25165824);
  bf16* wkt = (bf16*)(ws + 27262976);
  bf16* wvt = (bf16*)(ws + 29360128);
  bf16* wot = (bf16*)(ws + 31457280);
  bf16* qpp = (bf16*)(ws + 33554432);
  bf16* kpp = (bf16*)(ws + 41943040);
  bf16* vpp = (bf16*)(ws + 50331648);
  float* suf = (float*)(ws + 25165824);   // overlays wqt (dead after projections)
  int*  flg = (int*)(ws + 58720256);
  bf16* oa  = xq;

  const int n4 = (M_ * D_) / 4;
  convert3<<<dim3(4096, 1, 3), 256, 0, stream>>>(q_in, k_in, v_in, xq, xk, xv, n4);
  transpose4<<<dim3(16, 16, 4), 256, 0, stream>>>(Wq, Wk, Wv, Wo, wqt, wkt, wvt, wot);
  detect_mask<<<1, 256, 0, stream>>>((const unsigned int*)pmask, flg);

  gemm_k<128><<<dim3(8, 32, 3), 256, 0, stream>>>(xq, xk, xv, wqt, wkt, wvt,
                                                  bq, bk, bv, qpp, kpp, vpp, 0, D_, QSCALE);
  suf_kernel<<<32, 256, 0, stream>>>(vpp, suf);

  attn_kernel<<<512, 512, 0, stream>>>(qpp, kpp, vpp, suf, pmask, flg, oa);

  gemm_k<64><<<dim3(8, 64, 1), 256, 0, stream>>>(oa, oa, oa, wot, wot, wot,
                                                 bo, bo, bo, d_out, d_out, d_out, 2, D_, 1.f);
}

// Round 7
// 245.636 us; speedup vs baseline: 1.2855x; 1.1277x over previous
//
#include <hip/hip_runtime.h>
#include <hip/hip_bf16.h>
#include <cstdint>
#include <cstddef>

typedef __hip_bfloat16 bf16;
typedef __attribute__((ext_vector_type(8))) short short8;   // 8 bf16 = 4 VGPRs
typedef __attribute__((ext_vector_type(4))) short s4v;      // 4 bf16 = 2 VGPRs
typedef __attribute__((ext_vector_type(4))) float floatx4;

#define B_ 2
#define S_ 2048
#define D_ 1024
#define H_ 16
#define DK_ 64
#define M_ 4096
#define HEADELEMS 131072   // S_*DK_ per (b,h)
#define TILEELEMS 4096     // 64*64 per 64-token tile
#define QSCALE 0.1803368801111204f   // 0.125 * log2(e), folded into Q projection

struct __align__(8) bf16x4 { bf16 x, y, z, w; };

__device__ __forceinline__ floatx4 mfma16(short8 a, short8 b, floatx4 c) {
  return __builtin_amdgcn_mfma_f32_16x16x32_bf16(a, b, c, 0, 0, 0);
}
__device__ __forceinline__ void gl_lds16(const bf16* g, bf16* l) {
  __builtin_amdgcn_global_load_lds((const __attribute__((address_space(1))) void*)g,
                                   (__attribute__((address_space(3))) void*)l, 16, 0, 0);
}
__device__ __forceinline__ float bs2f(short s) {
  bf16 b = *reinterpret_cast<bf16*>(&s);
  return __bfloat162float(b);
}
__device__ __forceinline__ s4v pack4(float p0, float p1, float p2, float p3) {
  union { __hip_bfloat162 h; short2 s; } ua, ub;
  ua.h = __float22bfloat162_rn(make_float2(p0, p1));
  ub.h = __float22bfloat162_rn(make_float2(p2, p3));
  s4v r = {ua.s.x, ua.s.y, ub.s.x, ub.s.y};
  return r;
}

// ---------------- fused prep: fp32->bf16 converts + weight transposes + mask detect ----------------
// blocks [0,12288): converts (z = blk/4096); [12288,13312): transposes (z = (blk-12288)/256);
// block 13312: padding-mask dtype detector.
__global__ void prep_kernel(const float* __restrict__ q_in, const float* __restrict__ k_in,
                            const float* __restrict__ v_in,
                            const float* __restrict__ Wq, const float* __restrict__ Wk,
                            const float* __restrict__ Wv, const float* __restrict__ Wo,
                            bf16* __restrict__ xq, bf16* __restrict__ xk, bf16* __restrict__ xv,
                            bf16* __restrict__ wqt, bf16* __restrict__ wkt,
                            bf16* __restrict__ wvt, bf16* __restrict__ wot,
                            const unsigned int* __restrict__ pmask, int* __restrict__ flag) {
  __shared__ bf16 tile[64][66];
  __shared__ int sbyte;
  const int blk = blockIdx.x;
  const int tid = threadIdx.x;
  if (blk < 12288) {
    const int z = blk >> 12;
    const int i = ((blk & 4095) << 8) | tid;
    const float* src = (z == 0) ? q_in : (z == 1) ? k_in : v_in;
    bf16* dst = (z == 0) ? xq : (z == 1) ? xk : xv;
    float4 v = ((const float4*)src)[i];
    bf16x4 o = { __float2bfloat16(v.x), __float2bfloat16(v.y),
                 __float2bfloat16(v.z), __float2bfloat16(v.w) };
    ((bf16x4*)dst)[i] = o;
  } else if (blk < 13312) {
    const int t = blk - 12288;
    const int z = t >> 8;
    const int rc = t & 255;
    const int r0 = (rc >> 4) * 64, c0 = (rc & 15) * 64;
    const float* src = (z == 0) ? Wq : (z == 1) ? Wk : (z == 2) ? Wv : Wo;
    bf16* dst = (z == 0) ? wqt : (z == 1) ? wkt : (z == 2) ? wvt : wot;
    const int lr = tid >> 4;
    const int lc4 = (tid & 15) * 4;
#pragma unroll
    for (int i = 0; i < 4; ++i) {
      const int r = lr + i * 16;
      float4 v = *(const float4*)(src + (size_t)(r0 + r) * D_ + c0 + lc4);
      tile[r][lc4 + 0] = __float2bfloat16(v.x);
      tile[r][lc4 + 1] = __float2bfloat16(v.y);
      tile[r][lc4 + 2] = __float2bfloat16(v.z);
      tile[r][lc4 + 3] = __float2bfloat16(v.w);
    }
    __syncthreads();
    const int orr = tid & 63;
    const int oc0 = tid >> 6;
#pragma unroll
    for (int j = 0; j < 16; ++j) {
      const int oc = oc0 + j * 4;
      dst[(size_t)(c0 + oc) * D_ + r0 + orr] = tile[orr][oc];
    }
  } else {
    if (tid == 0) sbyte = 0;
    __syncthreads();
    for (int i = tid; i < (B_ * S_) / 4; i += 256) {
      const unsigned int v = pmask[i];
      if (((v & 0xFEFEFEFEu) == 0u) && ((v & 0xFFFFFF00u) != 0u)) sbyte = 1;
    }
    __syncthreads();
    if (tid == 0) *flag = sbyte;
  }
}

// ---------------- bf16 GEMM, C = A[M,K] * W[N,K]^T + bias ----------------
// mode 0: bf16 out, Q/K fragment-swizzled per-head tiles (LDS-bounced coalesced stores)
// mode 1: bf16 out, V^T fragment-swizzled per-head tiles (LDS-bounced coalesced stores)
// mode 2: fp32 out, plain [M][N]
template<int MT>
__global__ __launch_bounds__(256, 2) void gemm_k(
    const bf16* __restrict__ A0, const bf16* __restrict__ A1, const bf16* __restrict__ A2,
    const bf16* __restrict__ W0, const bf16* __restrict__ W1, const bf16* __restrict__ W2,
    const float* __restrict__ b0, const float* __restrict__ b1, const float* __restrict__ b2,
    void* __restrict__ O0, void* __restrict__ O1, void* __restrict__ O2,
    const int mode01, const int Kd, const float sc)
{
  __shared__ __align__(16) bf16 sh[(MT + 128) * 32];   // As | Bs, contiguous
  bf16* As = sh;
  bf16* Bs = sh + MT * 32;
  const int z = blockIdx.z;
  const bf16* A = (z == 0) ? A0 : (z == 1) ? A1 : A2;
  const bf16* W = (z == 0) ? W0 : (z == 1) ? W1 : W2;
  const float* bias = (z == 0) ? b0 : (z == 1) ? b1 : b2;
  void* Cout = (z == 0) ? O0 : (z == 1) ? O1 : O2;
  const int mode = (z == 2) ? 1 : mode01;
  const float scz = (z == 0) ? sc : 1.f;

  constexpr int MI = MT / 32;
  const int tid = threadIdx.x;
  const int wave = tid >> 6, lane = tid & 63;
  const int quad = lane >> 4, lc = lane & 15;
  const int wm = (wave >> 1) * (MT / 2), wn = (wave & 1) * 64;
  const int m0 = blockIdx.y * MT, n0 = blockIdx.x * 128;

  const floatx4 zero4 = {0.f, 0.f, 0.f, 0.f};
  floatx4 acc[MI][4];
#pragma unroll
  for (int mi = 0; mi < MI; ++mi)
#pragma unroll
    for (int ni = 0; ni < 4; ++ni) acc[mi][ni] = zero4;

  const int ldr = lane >> 2;
  const int ldc = (lane & 3) * 8;
  const bf16* Ag = A + (size_t)(m0 + wave * (MT / 4) + ldr) * Kd + ldc;
  const bf16* Bg = W + (size_t)(n0 + wave * 32 + ldr) * Kd + ldc;
  bf16* As0 = As + wave * (MT / 4) * 32;
  bf16* Bs0 = Bs + wave * 32 * 32;

  for (int k0 = 0; k0 < Kd; k0 += 32) {
    gl_lds16(Ag + k0, As0);
    if (MT == 128) gl_lds16(Ag + k0 + (size_t)16 * Kd, As0 + 16 * 32);
    gl_lds16(Bg + k0, Bs0);
    gl_lds16(Bg + k0 + (size_t)16 * Kd, Bs0 + 16 * 32);
    __syncthreads();

    short8 af[MI], bfr[4];
#pragma unroll
    for (int i = 0; i < MI; ++i)
      af[i] = *(const short8*)(As + (wm + i * 16 + lc) * 32 + quad * 8);
#pragma unroll
    for (int i = 0; i < 4; ++i)
      bfr[i] = *(const short8*)(Bs + (wn + i * 16 + lc) * 32 + quad * 8);
#pragma unroll
    for (int mi = 0; mi < MI; ++mi)
#pragma unroll
      for (int ni = 0; ni < 4; ++ni)
        acc[mi][ni] = mfma16(af[mi], bfr[ni], acc[mi][ni]);
    __syncthreads();
  }

  if (mode == 2) {
    float* out = (float*)Cout;
#pragma unroll
    for (int mi = 0; mi < MI; ++mi)
#pragma unroll
      for (int ni = 0; ni < 4; ++ni) {
        const int col = n0 + wn + ni * 16 + lc;
        const float bv = bias[col];
        const int rbase = m0 + wm + mi * 16 + quad * 4;
#pragma unroll
        for (int r = 0; r < 4; ++r)
          out[(size_t)(rbase + r) * D_ + col] = acc[mi][ni][r] + bv;
      }
  } else {
    // LDS-bounce: this wave's 64x64 quadrant == one (T, head) swizzled tile.
    bf16* pool = sh + wave * 2048;
    float bvs[4];
#pragma unroll
    for (int ni = 0; ni < 4; ++ni) bvs[ni] = bias[n0 + wn + ni * 16 + lc];
    const int hcol = (n0 + wn) >> 6;
    const int mglob = m0 + wm;
    bf16* outb = (bf16*)Cout + (size_t)((mglob >> 11) * H_ + hcol) * HEADELEMS
               + (size_t)((mglob & (S_ - 1)) >> 6) * TILEELEMS;
#pragma unroll
    for (int half = 0; half < MI / 2; ++half) {
#pragma unroll
      for (int mi2 = 0; mi2 < 2; ++mi2) {
        const int mi = half * 2 + mi2;
#pragma unroll
        for (int ni = 0; ni < 4; ++ni) {
          const int dkl = ni * 16 + lc;
#pragma unroll
          for (int r = 0; r < 4; ++r) {
            const float v = (acc[mi][ni][r] + bvs[ni]) * scz;
            int idx;
            if (mode == 0) {
              const int c = (mi2 * 2 + (dkl >> 5)) * 64 + ((dkl >> 3) & 3) * 16 + quad * 4 + r;
              idx = c * 8 + (dkl & 7);
            } else {
              const int c = (mi2 * 4 + (dkl >> 4)) * 64 + quad * 16 + (dkl & 15);
              idx = c * 4 + r;
            }
            pool[idx] = __float2bfloat16(v);
          }
        }
      }
#pragma unroll
      for (int t = 0; t < 4; ++t) {
        const short8 vv = *(const short8*)(pool + t * 512 + lane * 8);
        *(short8*)(outb + half * 2048 + t * 512 + lane * 8) = vv;
      }
    }
  }
}

// ---------------- V suffix sums ----------------
__global__ void suf_kernel(const bf16* __restrict__ vp, float* __restrict__ suf) {
  __shared__ float ts[32 * 64];
  const int bhid = blockIdx.x;
  const bf16* vb = vp + (size_t)bhid * HEADELEMS;
  const int tid = threadIdx.x;
  const int dk = tid & 63, g = tid >> 6;
  const int dkt = dk >> 4, lck = dk & 15;
  for (int T = g * 8; T < g * 8 + 8; ++T) {
    float sum = 0.f;
#pragma unroll
    for (int w = 0; w < 4; ++w)
#pragma unroll
      for (int qd = 0; qd < 4; ++qd) {
        const s4v x = *(const s4v*)(vb + (size_t)T * TILEELEMS
                                    + (size_t)(((w * 4 + dkt) * 64 + qd * 16 + lck)) * 4);
        sum += bs2f(x[0]) + bs2f(x[1]) + bs2f(x[2]) + bs2f(x[3]);
      }
    ts[T * 64 + dk] = sum;
  }
  __syncthreads();
  if (g == 0) {
    float run = 0.f;
    float* out = suf + (size_t)bhid * (33 * 64);
    out[32 * 64 + dk] = 0.f;
    for (int T = 31; T >= 0; --T) { run += ts[T * 64 + dk]; out[T * 64 + dk] = run; }
  }
}

// ---------------- fused attention ----------------
__device__ __forceinline__ void load_pad(const void* pad, int bytemode, int idx, bool pm[4]) {
  if (bytemode) {
    const uchar4 u = *(const uchar4*)((const unsigned char*)pad + idx);
    pm[0] = u.x != 0; pm[1] = u.y != 0; pm[2] = u.z != 0; pm[3] = u.w != 0;
  } else {
    const int4 u = *(const int4*)((const int*)pad + idx);
    pm[0] = u.x != 0; pm[1] = u.y != 0; pm[2] = u.z != 0; pm[3] = u.w != 0;
  }
}

// S^T = K*Q^T for one 64-key tile (wave owns 16-key strip); mask+exp -> pf (P^T, B-frag-ready)
// Q pre-scaled by 0.125*log2(e) at projection time.
__device__ __forceinline__ void qk_tile(const short8 ak0, const short8 ak1,
                                        const short8 (&qf)[4][2],
                                        const bool pm[4], float (&lacc)[4], s4v (&pf)[4],
                                        const int w, const int quad, const int lc,
                                        const bool diag) {
  const floatx4 z4 = {0.f, 0.f, 0.f, 0.f};
  const short ONE = (short)0x3F80;
#pragma unroll
  for (int qt = 0; qt < 4; ++qt) {
    if (diag && w > qt) {          // strictly-upper 16x16 subtile: all masked -> p = 1
      s4v o1 = {ONE, ONE, ONE, ONE};
      pf[qt] = o1;
      lacc[qt] += 4.f;
      continue;
    }
    floatx4 s = mfma16(ak0, qf[qt][0], z4);
    s = mfma16(ak1, qf[qt][1], s);
    float pv[4];
#pragma unroll
    for (int r = 0; r < 4; ++r) {
      bool m = pm[r];
      if (diag && w == qt) m = m || (quad * 4 + r > lc);
      pv[r] = exp2f(m ? 0.f : s[r]);
      lacc[qt] += pv[r];
    }
    pf[qt] = pack4(pv[0], pv[1], pv[2], pv[3]);
  }
}

// Barrier-free main loop: each wave loads its own K/V fragments DIRECTLY from the
// swizzled global layout (coalesced dwordx4/dwordx2, L2-local via XCD swizzle) —
// no LDS, no __syncthreads until the epilogue. 256 threads = 4 key-strip waves,
// one q-tile per block. Grid 1024: lin&7 = XCD = bh&7; per-CU q-tile set
// {31-c, c, 31-((c+16)&31), (c+16)&31} bounds CU makespan at the max single block.
__global__ __launch_bounds__(256, 2) void attn_kernel(
    const bf16* __restrict__ qp, const bf16* __restrict__ kp,
    const bf16* __restrict__ vp, const float* __restrict__ suf,
    const void* __restrict__ pad, const int* __restrict__ flag,
    bf16* __restrict__ oa)
{
  __shared__ __align__(16) bf16 smem[12800];   // epilogue only: fbuf 16KB | obuf 9216B
  __shared__ float lbuf[256];

  const int lin = blockIdx.x;
  const int xcd = lin & 7;
  const int i2 = lin >> 3;             // 0..127
  const int grp = i2 >> 5;             // 0..3
  const int r5 = i2 & 31;
  const int bh = xcd + 8 * grp;
  const int rr = (grp & 2) ? ((r5 + 16) & 31) : r5;
  const int myqt = (grp & 1) ? rr : (31 - rr);
  const int b = bh >> 4, h = bh & 15;

  const int mynt = myqt + 1;
  const int mynp = (mynt + 1) >> 1;
  const int tid = threadIdx.x;
  const int w = tid >> 6, lane = tid & 63, quad = lane >> 4, lc = lane & 15;
  const int bytemode = *flag;
  const int padbase = b * S_;

  // Q fragments (B-operand for S^T = K*Q^T), fragment-linear in global
  const bf16* qb = qp + (size_t)bh * HEADELEMS + (size_t)myqt * TILEELEMS;
  short8 qf[4][2];
#pragma unroll
  for (int qt = 0; qt < 4; ++qt)
#pragma unroll
    for (int hh = 0; hh < 2; ++hh)
      qf[qt][hh] = *(const short8*)(qb + (size_t)((qt * 2 + hh) * 64 + lane) * 8);

  // per-wave direct-load base pointers into swizzled K / V^T
  const bf16* kwp = kp + (size_t)bh * HEADELEMS + (size_t)(w * 128 + lane) * 8;
  const bf16* vwp = vp + (size_t)bh * HEADELEMS + (size_t)(w * 4 * 64 + lane) * 4;

  const floatx4 zero4 = {0.f, 0.f, 0.f, 0.f};
  floatx4 oacc[4][4];                            // [dkt][qt]
#pragma unroll
  for (int i = 0; i < 4; ++i)
#pragma unroll
    for (int jj = 0; jj < 4; ++jj) oacc[i][jj] = zero4;
  float lacc[4] = {0.f, 0.f, 0.f, 0.f};

  for (int p = 0; p < mynp; ++p) {
    const int T0 = 2 * p, T1 = 2 * p + 1;
    const size_t o0 = (size_t)T0 * TILEELEMS, o1 = o0 + TILEELEMS;
    // K fragments for this wave's 16-key strips of both tiles (4 x dwordx4)
    const short8 ak00 = *(const short8*)(kwp + o0);
    const short8 ak01 = *(const short8*)(kwp + o0 + 512);
    const short8 ak10 = *(const short8*)(kwp + o1);
    const short8 ak11 = *(const short8*)(kwp + o1 + 512);
    // V^T fragments (8 x dwordx2)
    s4v va0[4], va1[4];
#pragma unroll
    for (int dkt = 0; dkt < 4; ++dkt) {
      va0[dkt] = *(const s4v*)(vwp + o0 + dkt * 256);
      va1[dkt] = *(const s4v*)(vwp + o1 + dkt * 256);
    }

    bool pm[4];
    s4v pf0[4], pf1[4];
    load_pad(pad, bytemode, padbase + T0 * 64 + w * 16 + quad * 4, pm);
    qk_tile(ak00, ak01, qf, pm, lacc, pf0, w, quad, lc, T0 == mynt - 1);
    if (T1 < mynt) {
      load_pad(pad, bytemode, padbase + T1 * 64 + w * 16 + quad * 4, pm);
      qk_tile(ak10, ak11, qf, pm, lacc, pf1, w, quad, lc, T1 == mynt - 1);
    } else {
      const s4v zz = {0, 0, 0, 0};
#pragma unroll
      for (int qt = 0; qt < 4; ++qt) pf1[qt] = zz;   // phantom: covered by suffix sums
    }

    short8 pB[4];
#pragma unroll
    for (int qt = 0; qt < 4; ++qt)
      pB[qt] = __builtin_shufflevector(pf0[qt], pf1[qt], 0, 1, 2, 3, 4, 5, 6, 7);
#pragma unroll
    for (int dkt = 0; dkt < 4; ++dkt) {
      const short8 av = __builtin_shufflevector(va0[dkt], va1[dkt], 0, 1, 2, 3, 4, 5, 6, 7);
#pragma unroll
      for (int qt = 0; qt < 4; ++qt)
        oacc[dkt][qt] = mfma16(av, pB[qt], oacc[dkt][qt]);
    }
  }

  // ---- epilogue: cross-strip reduction -> LDS out-tile -> full-128B-line stores ----
#pragma unroll
  for (int qt = 0; qt < 4; ++qt) {
    float v = lacc[qt];
    v += __shfl_xor(v, 16);
    v += __shfl_xor(v, 32);
    if (quad == 0) lbuf[w * 64 + qt * 16 + lc] = v;
  }
  __syncthreads();
  float* fbuf = (float*)smem;                    // 4096 floats = 16 KB
  bf16* obuf = smem + 8192;                      // 64 rows x stride 72 = 9216 B
  float ls = lbuf[0 * 64 + w * 16 + lc] + lbuf[1 * 64 + w * 16 + lc]
           + lbuf[2 * 64 + w * 16 + lc] + lbuf[3 * 64 + w * 16 + lc];
  ls += (float)(S_ - mynt * 64);                 // keys past diagonal tile: weight 1 each
  const float linv = 1.f / ls;
  const float* sufp = suf + (size_t)bh * (33 * 64) + mynt * 64;

#pragma unroll
  for (int dktG = 0; dktG < 4; ++dktG) {
#pragma unroll
    for (int qt = 0; qt < 4; ++qt) {
      const floatx4 a = oacc[dktG][qt];
      float* dst = fbuf + (w * 4 + qt) * 256 + lc;
#pragma unroll
      for (int r = 0; r < 4; ++r) dst[(quad * 4 + r) * 16] = a[r];
    }
    __syncthreads();
    // wave w reduces tiles qt == w across the 4 strips
    const float4 sv4 = *(const float4*)(sufp + dktG * 16 + quad * 4);
    float v[4];
#pragma unroll
    for (int r = 0; r < 4; ++r) {
      const int e = (quad * 4 + r) * 16 + lc;
      v[r] = fbuf[(0 * 4 + w) * 256 + e] + fbuf[(1 * 4 + w) * 256 + e]
           + fbuf[(2 * 4 + w) * 256 + e] + fbuf[(3 * 4 + w) * 256 + e];
    }
    v[0] = (v[0] + sv4.x) * linv; v[1] = (v[1] + sv4.y) * linv;
    v[2] = (v[2] + sv4.z) * linv; v[3] = (v[3] + sv4.w) * linv;
    bf16x4 pk = { __float2bfloat16(v[0]), __float2bfloat16(v[1]),
                  __float2bfloat16(v[2]), __float2bfloat16(v[3]) };
    *(bf16x4*)(obuf + (w * 16 + lc) * 72 + dktG * 16 + quad * 4) = pk;
    __syncthreads();
  }

  // store: 2 instructions, each = 8 rows x 128B full lines
  const size_t obase = (size_t)(b * S_ + myqt * 64) * D_ + h * 64;
#pragma unroll
  for (int it = 0; it < 2; ++it) {
    const int idx = it * 256 + tid;
    const int row = idx >> 3, c8 = (idx & 7) * 8;
    const short8 vv = *(const short8*)(obuf + row * 72 + c8);
    *(short8*)(oa + obase + (size_t)row * D_ + c8) = vv;
  }
}

extern "C" void kernel_launch(void* const* d_in, const int* in_sizes, int n_in,
                              void* d_out, int out_size, void* d_ws, size_t ws_size,
                              hipStream_t stream) {
  (void)in_sizes; (void)n_in; (void)out_size; (void)ws_size;
  const float* q_in = (const float*)d_in[0];
  const float* k_in = (const float*)d_in[1];
  const float* v_in = (const float*)d_in[2];
  const void*  pmask = d_in[3];
  const float* Wq = (const float*)d_in[4];
  const float* bq = (const float*)d_in[5];
  const float* Wk = (const float*)d_in[6];
  const float* bk = (const float*)d_in[7];
  const float* Wv = (const float*)d_in[8];
  const float* bv = (const float*)d_in[9];
  const float* Wo = (const float*)d_in[10];
  const float* bo = (const float*)d_in[11];

  char* ws = (char*)d_ws;
  bf16* xq  = (bf16*)(ws + 0);
  bf16* xk  = (bf16*)(ws + 8388608);
  bf16* xv  = (bf16*)(ws + 16777216);
  bf16* wqt = (bf16*)(ws + 25165824);
  bf16* wkt = (bf16*)(ws + 27262976);
  bf16* wvt = (bf16*)(ws + 29360128);
  bf16* wot = (bf16*)(ws + 31457280);
  bf16* qpp = (bf16*)(ws + 33554432);
  bf16* kpp = (bf16*)(ws + 41943040);
  bf16* vpp = (bf16*)(ws + 50331648);
  float* suf = (float*)(ws + 25165824);   // overlays wqt (dead after projections)
  int*  flg = (int*)(ws + 58720256);
  bf16* oa  = xq;

  prep_kernel<<<13313, 256, 0, stream>>>(q_in, k_in, v_in, Wq, Wk, Wv, Wo,
                                         xq, xk, xv, wqt, wkt, wvt, wot,
                                         (const unsigned int*)pmask, flg);

  gemm_k<128><<<dim3(8, 32, 3), 256, 0, stream>>>(xq, xk, xv, wqt, wkt, wvt,
                                                  bq, bk, bv, qpp, kpp, vpp, 0, D_, QSCALE);
  suf_kernel<<<32, 256, 0, stream>>>(vpp, suf);

  attn_kernel<<<1024, 256, 0, stream>>>(qpp, kpp, vpp, suf, pmask, flg, oa);

  gemm_k<64><<<dim3(8, 64, 1), 256, 0, stream>>>(oa, oa, oa, wot, wot, wot,
                                                 bo, bo, bo, d_out, d_out, d_out, 2, D_, 1.f);
}